// Round 13
// baseline (138.638 us; speedup 1.0000x reference)
//
#include <hip/hip_runtime.h>

// Round 13: occupancy-max on the two GEMMs (round-12 mechanism, finer tiles):
//   gin  64x128 -> 64x64  (LDS 48->32 KB, grid 768->1536, ~5 blocks/CU)
//   gout 64x64  -> 32x64  (LDS 32->24 KB, grid 512->1024,  4 blocks/CU)
// Counted-vmcnt 2-deep kept everywhere (gin stage=4 -> WAIT_VM(4), gout
// stage=3 -> WAIT_VM(3)). cast / attn byte-identical to round 12.

#define E_DIM 1024

typedef short bf16x8 __attribute__((ext_vector_type(8)));
typedef float f32x4  __attribute__((ext_vector_type(4)));

__device__ inline unsigned short f2bf(float f) {
    unsigned u = __builtin_bit_cast(unsigned, f);
    u = (u + 0x7FFFu + ((u >> 16) & 1u)) >> 16;   // RNE; inputs finite
    return (unsigned short)u;
}

__device__ inline void gload_lds16(const void* g, void* l) {
    __builtin_amdgcn_global_load_lds(
        (const __attribute__((address_space(1))) unsigned int*)g,
        (__attribute__((address_space(3))) unsigned int*)l, 16, 0, 0);
}

// XOR swizzle within each 8-row stripe of a 128B-stride tile (involution).
__device__ inline int swzb(int row, int colbyte) {
    return colbyte ^ ((row & 7) << 4);
}

#define WAIT_VM(N) do { \
    asm volatile("s_waitcnt vmcnt(" #N ")" ::: "memory"); \
    __builtin_amdgcn_sched_barrier(0); } while (0)

// ---------------------------------------------------------------------------
// Kernel 0: cast everything to bf16, contiguous dst:
//   [xq 2M][xk 2M][xv 2M][Wi 3M][Wo 1M] elements.
// ---------------------------------------------------------------------------
__global__ __launch_bounds__(256) void k_cast(
    const float* __restrict__ q_in, const float* __restrict__ k_in,
    const float* __restrict__ v_in, const float* __restrict__ w_in,
    const float* __restrict__ w_out, unsigned short* __restrict__ dst)
{
    #pragma unroll
    for (int l = 0; l < 4; ++l) {
        int id8 = blockIdx.x * 256 + threadIdx.x + l * 327680;
        const float* src;
        if (id8 < 262144)        src = q_in  + (size_t)id8 * 8;
        else if (id8 < 524288)   src = k_in  + (size_t)(id8 - 262144) * 8;
        else if (id8 < 786432)   src = v_in  + (size_t)(id8 - 524288) * 8;
        else if (id8 < 1179648)  src = w_in  + (size_t)(id8 - 786432) * 8;
        else                     src = w_out + (size_t)(id8 - 1179648) * 8;
        float4 f0 = *reinterpret_cast<const float4*>(src);
        float4 f1 = *reinterpret_cast<const float4*>(src + 4);
        ushort4 o0, o1;
        o0.x = f2bf(f0.x); o0.y = f2bf(f0.y); o0.z = f2bf(f0.z); o0.w = f2bf(f0.w);
        o1.x = f2bf(f1.x); o1.y = f2bf(f1.y); o1.z = f2bf(f1.z); o1.w = f2bf(f1.w);
        *reinterpret_cast<ushort4*>(dst + (size_t)id8 * 8)     = o0;
        *reinterpret_cast<ushort4*>(dst + (size_t)id8 * 8 + 4) = o1;
    }
}

// ---------------------------------------------------------------------------
// Kernel 1: in-projection GEMM, 64x64 tile, BK=64, counted-vmcnt 2-deep,
// LDS 32 KB -> ~5 blocks/CU. Grid 1536 (8 XCD x 192), x-inner chunking
// (16 n-tiles share one A row-tile; W z-slab 2MB L2-resident per XCD).
// Stage = 4 gload_lds/thread (B 2 + A 2). 4 waves (2x2), 32x32 out each.
// Epilogue: z=0 Q natural; z=1 K natural + Kt; z=2 Vt only.
// ---------------------------------------------------------------------------
__global__ __launch_bounds__(256) void k_gin(
    const unsigned short* __restrict__ xbf, const unsigned short* __restrict__ Wibf,
    const float* __restrict__ b_in,
    unsigned short* __restrict__ qslab, unsigned short* __restrict__ kslab,
    unsigned short* __restrict__ ktb,   unsigned short* __restrict__ vtb)
{
    const int i = blockIdx.x;
    const int tile = (i & 7) * 192 + (i >> 3);    // 1536 = 8 XCD * 192
    const int z = tile >> 9;                      // 512 tiles per z
    const int r = tile & 511;
    const int y = r >> 4, x = r & 15;             // x-inner: 16 n-tiles share A row-tile

    const unsigned short* X = xbf + (size_t)z * 2097152;
    const unsigned short* W = Wibf + (size_t)z * 1048576;
    const float* bz = b_in + z * E_DIM;

    const int nBase = x * 64;
    const int mBase = y * 64;                     // b-major row space
    const int b = mBase >> 10, tBase = mBase & 1023;

    __shared__ short As[2][64 * 64];              // 2 x 8 KB
    __shared__ short Bs[2][64 * 64];              // 2 x 8 KB  (32 KB total)

    const int tid = threadIdx.x;
    const int lane = tid & 63, wave = tid >> 6;
    const int wr = wave >> 1, wc = wave & 1;
    const int l15 = lane & 15, l4 = lane >> 4;

    auto stage = [&](int bufI, int it) {
        int k0 = it * 64;
        #pragma unroll
        for (int l = 0; l < 2; ++l) {             // B: 64x64 bf16 = 8 KB
            int off = l * 4096 + tid * 16;
            int row = off >> 7, cb = off & 127;
            gload_lds16((const char*)W + ((size_t)(nBase + row) * E_DIM + k0) * 2
                            + swzb(row, cb),
                        (char*)&Bs[bufI][0] + off);
        }
        #pragma unroll
        for (int l = 0; l < 2; ++l) {             // A: 64x64 bf16 = 8 KB
            int off = l * 4096 + tid * 16;
            int row = off >> 7, cb = off & 127;
            gload_lds16((const char*)X +
                            ((size_t)((tBase + row) * 2 + b) * E_DIM + k0) * 2
                            + swzb(row, cb),
                        (char*)&As[bufI][0] + off);
        }
    };

    f32x4 acc[2][2] = {};

    stage(0, 0);
    stage(1, 1);
    for (int it = 0; it < 16; ++it) {
        if (it < 15) WAIT_VM(4); else WAIT_VM(0);    // tile it landed (mine)
        __builtin_amdgcn_s_barrier();                // ...and everyone's
        const int cur = it & 1;
        #pragma unroll
        for (int kk = 0; kk < 64; kk += 32) {
            bf16x8 af[2], bfr[2];
            #pragma unroll
            for (int ii = 0; ii < 2; ++ii) {
                int row = wr * 32 + ii * 16 + l15;
                af[ii] = *reinterpret_cast<const bf16x8*>(
                    &As[cur][row * 64 + (swzb(row, (kk + l4 * 8) * 2) >> 1)]);
            }
            #pragma unroll
            for (int jn = 0; jn < 2; ++jn) {
                int row = wc * 32 + jn * 16 + l15;
                bfr[jn] = *reinterpret_cast<const bf16x8*>(
                    &Bs[cur][row * 64 + (swzb(row, (kk + l4 * 8) * 2) >> 1)]);
            }
            #pragma unroll
            for (int ii = 0; ii < 2; ++ii)
                #pragma unroll
                for (int jn = 0; jn < 2; ++jn)
                    acc[ii][jn] = __builtin_amdgcn_mfma_f32_16x16x32_bf16(
                        af[ii], bfr[jn], acc[ii][jn], 0, 0, 0);
        }
        __builtin_amdgcn_s_barrier();                // all reads of cur done
        __builtin_amdgcn_sched_barrier(0);
        if (it + 2 < 16) stage(cur, it + 2);         // refill freed buffer
    }

    #pragma unroll
    for (int ii = 0; ii < 2; ++ii) {
        int t0 = tBase + wr * 32 + ii * 16 + l4 * 4;
        #pragma unroll
        for (int jn = 0; jn < 2; ++jn) {
            int col = nBase + wc * 32 + jn * 16 + l15;
            float bv = bz[col];
            unsigned short v4[4];
            #pragma unroll
            for (int q = 0; q < 4; ++q) v4[q] = f2bf(acc[ii][jn][q] + bv);
            if (z == 0) {
                #pragma unroll
                for (int q = 0; q < 4; ++q)
                    qslab[(size_t)b * 1048576 + (size_t)(t0 + q) * E_DIM + col] = v4[q];
            } else if (z == 1) {
                #pragma unroll
                for (int q = 0; q < 4; ++q)
                    kslab[(size_t)b * 1048576 + (size_t)(t0 + q) * E_DIM + col] = v4[q];
                ushort4 w = {v4[0], v4[1], v4[2], v4[3]};
                *reinterpret_cast<ushort4*>(
                    &ktb[((size_t)b * 1024 + col) * 1024 + t0]) = w;
            } else {
                ushort4 w = {v4[0], v4[1], v4[2], v4[3]};
                *reinterpret_cast<ushort4*>(
                    &vtb[((size_t)b * 1024 + col) * 1024 + t0]) = w;
            }
        }
    }
}

// ---------------------------------------------------------------------------
// Kernel 2: chunked-prefix linear attention, counted-vmcnt 2-deep P-loop.
// Tiles tau = 0..qt: tau<qt -> P chunk (Kt,Vt); tau==qt -> diag (K nat, Vt).
// Stage = 4 gload_lds/thread. Grid 512, XCD-chunked, complementary pairing.
// ---------------------------------------------------------------------------
__global__ __launch_bounds__(256) void k_attn(
    const unsigned short* __restrict__ qslab, const unsigned short* __restrict__ kslab,
    const unsigned short* __restrict__ ktb,  const unsigned short* __restrict__ vtb,
    unsigned short* __restrict__ attnbf)
{
    const int i = blockIdx.x;
    const int xcd = i & 7, u = i >> 3;            // u in 0..63
    const int bh = xcd * 4 + (u >> 4);
    const int qtr = u & 15;
    const int qt = ((u >> 5) & 1) ? (15 - qtr) : qtr;
    const int b = bh >> 4, h = bh & 15;
    const int colb = h * 64, t0q = qt * 64;

    __shared__ short Qs[64 * 64];
    __shared__ short KB[2][64 * 64];              // Kt tiles / diag K natural
    __shared__ short VB[2][64 * 64];              // Vt tiles
    __shared__ short Ss[64 * 72];                 // masked S (padded)
    __shared__ short PTs[64 * 72];                // P^T bf16 (padded)

    const int tid = threadIdx.x;
    const int lane = tid & 63, wave = tid >> 6;
    const int wr = wave >> 1, wc = wave & 1;
    const int l15 = lane & 15, l4 = lane >> 4;

    // unified tile stage: tau < qt -> P chunk; tau == qt -> diag
    auto stage = [&](int bufI, int tau) {
        #pragma unroll
        for (int l = 0; l < 2; ++l) {
            int off = l * 4096 + tid * 16;
            int row = off >> 7, cb = off & 127;
            int scb = swzb(row, cb);
            if (tau < qt) {
                size_t trn = ((size_t)(b * 1024 + colb + row)) * 1024 + tau * 64;
                gload_lds16((const char*)ktb + trn * 2 + scb, (char*)&KB[bufI][0] + off);
                gload_lds16((const char*)vtb + trn * 2 + scb, (char*)&VB[bufI][0] + off);
            } else {
                gload_lds16((const char*)kslab +
                                ((size_t)b * 1048576 + (size_t)(t0q + row) * E_DIM + colb) * 2 + scb,
                            (char*)&KB[bufI][0] + off);
                gload_lds16((const char*)vtb +
                                (((size_t)(b * 1024 + colb + row)) * 1024 + t0q) * 2 + scb,
                            (char*)&VB[bufI][0] + off);
            }
        }
    };

    #pragma unroll
    for (int l = 0; l < 2; ++l) {                 // stage Q once (2 ops)
        int off = l * 4096 + tid * 16;
        int row = off >> 7, cb = off & 127;
        gload_lds16((const char*)qslab +
                        ((size_t)b * 1048576 + (size_t)(t0q + row) * E_DIM + colb) * 2
                        + swzb(row, cb),
                    (char*)Qs + off);
    }
    stage(0, 0);
    if (qt >= 1) stage(1, 1);

    f32x4 pacc[2][2] = {};                        // P[dk][dv] fp32

    // P accumulation over tau = 0..qt-1 (counted vmcnt: next tile always in flight)
    for (int tau = 0; tau < qt; ++tau) {
        WAIT_VM(4);                               // tile tau landed (mine)
        __builtin_amdgcn_s_barrier();
        const int cur = tau & 1;
        #pragma unroll
        for (int kk = 0; kk < 64; kk += 32) {
            bf16x8 af[2], bfr[2];
            #pragma unroll
            for (int ii = 0; ii < 2; ++ii) {
                int row = wr * 32 + ii * 16 + l15;     // dk
                af[ii] = *reinterpret_cast<const bf16x8*>(
                    &KB[cur][row * 64 + (swzb(row, (kk + l4 * 8) * 2) >> 1)]);
            }
            #pragma unroll
            for (int jn = 0; jn < 2; ++jn) {
                int row = wc * 32 + jn * 16 + l15;     // dv
                bfr[jn] = *reinterpret_cast<const bf16x8*>(
                    &VB[cur][row * 64 + (swzb(row, (kk + l4 * 8) * 2) >> 1)]);
            }
            #pragma unroll
            for (int ii = 0; ii < 2; ++ii)
                #pragma unroll
                for (int jn = 0; jn < 2; ++jn)
                    pacc[ii][jn] = __builtin_amdgcn_mfma_f32_16x16x32_bf16(
                        af[ii], bfr[jn], pacc[ii][jn], 0, 0, 0);
        }
        __builtin_amdgcn_s_barrier();
        __builtin_amdgcn_sched_barrier(0);
        if (tau + 2 <= qt) stage(cur, tau + 2);
    }

    // diag tile (tau = qt) in buf[qt&1]
    WAIT_VM(0);
    __builtin_amdgcn_s_barrier();
    const int dcur = qt & 1;

    f32x4 sacc[2][2] = {};
    #pragma unroll
    for (int kk = 0; kk < 64; kk += 32) {
        bf16x8 af[2], bfr[2];
        #pragma unroll
        for (int ii = 0; ii < 2; ++ii) {
            int row = wr * 32 + ii * 16 + l15;         // t
            af[ii] = *reinterpret_cast<const bf16x8*>(
                &Qs[row * 64 + (swzb(row, (kk + l4 * 8) * 2) >> 1)]);
        }
        #pragma unroll
        for (int jn = 0; jn < 2; ++jn) {
            int row = wc * 32 + jn * 16 + l15;         // tk
            bfr[jn] = *reinterpret_cast<const bf16x8*>(
                &KB[dcur][row * 64 + (swzb(row, (kk + l4 * 8) * 2) >> 1)]);
        }
        #pragma unroll
        for (int ii = 0; ii < 2; ++ii)
            #pragma unroll
            for (int jn = 0; jn < 2; ++jn)
                sacc[ii][jn] = __builtin_amdgcn_mfma_f32_16x16x32_bf16(
                    af[ii], bfr[jn], sacc[ii][jn], 0, 0, 0);
    }

    // write P^T (bf16) and masked S to LDS
    #pragma unroll
    for (int ii = 0; ii < 2; ++ii) {
        #pragma unroll
        for (int jn = 0; jn < 2; ++jn) {
            int dv = wc * 32 + jn * 16 + l15;
            int dkb = wr * 32 + ii * 16 + l4 * 4;
            ushort4 pw;
            pw.x = f2bf(pacc[ii][jn][0]); pw.y = f2bf(pacc[ii][jn][1]);
            pw.z = f2bf(pacc[ii][jn][2]); pw.w = f2bf(pacc[ii][jn][3]);
            *reinterpret_cast<ushort4*>(&PTs[dv * 72 + dkb]) = pw;
            int kr = dv;
            #pragma unroll
            for (int q = 0; q < 4; ++q) {
                int qr = dkb + q;
                Ss[qr * 72 + kr] = (kr <= qr) ? (short)f2bf(sacc[ii][jn][q]) : (short)0;
            }
        }
    }
    __syncthreads();

    // O = S @ Vqt + Q @ P
    f32x4 oacc[2][2] = {};
    #pragma unroll
    for (int kk = 0; kk < 64; kk += 32) {
        bf16x8 af[2], bfr[2];
        #pragma unroll
        for (int ii = 0; ii < 2; ++ii)
            af[ii] = *reinterpret_cast<const bf16x8*>(
                        &Ss[(wr * 32 + ii * 16 + l15) * 72 + kk + l4 * 8]);
        #pragma unroll
        for (int jn = 0; jn < 2; ++jn) {
            int row = wc * 32 + jn * 16 + l15;         // dv
            bfr[jn] = *reinterpret_cast<const bf16x8*>(
                &VB[dcur][row * 64 + (swzb(row, (kk + l4 * 8) * 2) >> 1)]);
        }
        #pragma unroll
        for (int ii = 0; ii < 2; ++ii)
            #pragma unroll
            for (int jn = 0; jn < 2; ++jn)
                oacc[ii][jn] = __builtin_amdgcn_mfma_f32_16x16x32_bf16(
                    af[ii], bfr[jn], oacc[ii][jn], 0, 0, 0);
    }
    #pragma unroll
    for (int kk = 0; kk < 64; kk += 32) {
        bf16x8 af[2], bfr[2];
        #pragma unroll
        for (int ii = 0; ii < 2; ++ii) {
            int row = wr * 32 + ii * 16 + l15;         // t
            af[ii] = *reinterpret_cast<const bf16x8*>(
                &Qs[row * 64 + (swzb(row, (kk + l4 * 8) * 2) >> 1)]);
        }
        #pragma unroll
        for (int jn = 0; jn < 2; ++jn)
            bfr[jn] = *reinterpret_cast<const bf16x8*>(
                        &PTs[(wc * 32 + jn * 16 + l15) * 72 + kk + l4 * 8]);
        #pragma unroll
        for (int ii = 0; ii < 2; ++ii)
            #pragma unroll
            for (int jn = 0; jn < 2; ++jn)
                oacc[ii][jn] = __builtin_amdgcn_mfma_f32_16x16x32_bf16(
                    af[ii], bfr[jn], oacc[ii][jn], 0, 0, 0);
    }

    #pragma unroll
    for (int ii = 0; ii < 2; ++ii) {
        #pragma unroll
        for (int jn = 0; jn < 2; ++jn) {
            int dv = wc * 32 + jn * 16 + l15;
            #pragma unroll
            for (int q = 0; q < 4; ++q) {
                int qr = wr * 32 + ii * 16 + l4 * 4 + q;
                attnbf[(size_t)b * 1048576 + (size_t)(t0q + qr) * E_DIM + colb + dv] =
                    f2bf(oacc[ii][jn][q] * 0.125f);
            }
        }
    }
}

// ---------------------------------------------------------------------------
// Kernel 3: out-projection GEMM, 32x64 tile, counted-vmcnt 2-deep,
// LDS 24 KB, grid 1024 (4 blocks/CU). Stage = 3 gload_lds/thread (B 2 + A 1).
// 4 waves (2x2), each 16x32 out. fp32 out rows r = t*2+b.
// ---------------------------------------------------------------------------
__global__ __launch_bounds__(256) void k_gout(
    const unsigned short* __restrict__ attnbf, const unsigned short* __restrict__ Wobf,
    const float* __restrict__ bias, float* __restrict__ out)
{
    const int i = blockIdx.x;
    const int tile = (i & 7) * 128 + (i >> 3);    // 1024 = 8 * 128
    const int x = tile & 15, y = tile >> 4;       // 16 n-tiles, 64 m-tiles
    const int nBase = x * 64;
    const int mBase = y * 32;                     // r-space (t*2+b)

    __shared__ short As[2][32 * 64];              // 2 x 4 KB
    __shared__ short Bs[2][64 * 64];              // 2 x 8 KB  (24 KB total)

    const int tid = threadIdx.x;
    const int lane = tid & 63, wave = tid >> 6;
    const int wr = wave >> 1, wc = wave & 1;
    const int l15 = lane & 15, l4 = lane >> 4;

    auto stage = [&](int bufI, int it) {
        int k0 = it * 64;
        #pragma unroll
        for (int l = 0; l < 2; ++l) {             // B: 64x64 bf16 = 8 KB
            int off = l * 4096 + tid * 16;
            int row = off >> 7, cb = off & 127;
            gload_lds16((const char*)Wobf + ((size_t)(nBase + row) * E_DIM + k0) * 2
                            + swzb(row, cb),
                        (char*)&Bs[bufI][0] + off);
        }
        {                                         // A: 32x64 bf16 = 4 KB (1 op)
            int off = tid * 16;
            int row = off >> 7, cb = off & 127;
            int r = mBase + row, t = r >> 1, bb = r & 1;
            gload_lds16((const char*)attnbf +
                            ((size_t)bb * 1048576 + (size_t)t * E_DIM + k0) * 2
                            + swzb(row, cb),
                        (char*)&As[bufI][0] + off);
        }
    };

    f32x4 acc[2] = {};

    stage(0, 0);
    stage(1, 1);
    for (int it = 0; it < 16; ++it) {
        if (it < 15) WAIT_VM(3); else WAIT_VM(0);
        __builtin_amdgcn_s_barrier();
        const int cur = it & 1;
        #pragma unroll
        for (int kk = 0; kk < 64; kk += 32) {
            bf16x8 af, bfr[2];
            {
                int row = wr * 16 + l15;
                af = *reinterpret_cast<const bf16x8*>(
                    &As[cur][row * 64 + (swzb(row, (kk + l4 * 8) * 2) >> 1)]);
            }
            #pragma unroll
            for (int jn = 0; jn < 2; ++jn) {
                int row = wc * 32 + jn * 16 + l15;
                bfr[jn] = *reinterpret_cast<const bf16x8*>(
                    &Bs[cur][row * 64 + (swzb(row, (kk + l4 * 8) * 2) >> 1)]);
            }
            #pragma unroll
            for (int jn = 0; jn < 2; ++jn)
                acc[jn] = __builtin_amdgcn_mfma_f32_16x16x32_bf16(
                    af, bfr[jn], acc[jn], 0, 0, 0);
        }
        __builtin_amdgcn_s_barrier();
        __builtin_amdgcn_sched_barrier(0);
        if (it + 2 < 16) stage(cur, it + 2);
    }

    {
        int r0 = mBase + wr * 16 + l4 * 4;
        #pragma unroll
        for (int jn = 0; jn < 2; ++jn) {
            int col = nBase + wc * 32 + jn * 16 + l15;
            float bv = bias[col];
            #pragma unroll
            for (int q = 0; q < 4; ++q)
                out[(size_t)(r0 + q) * E_DIM + col] = acc[jn][q] + bv;
        }
    }
}

// ---------------------------------------------------------------------------
extern "C" void kernel_launch(void* const* d_in, const int* in_sizes, int n_in,
                              void* d_out, int out_size, void* d_ws, size_t ws_size,
                              hipStream_t stream)
{
    const float* q_in  = (const float*)d_in[0];
    const float* k_in  = (const float*)d_in[1];
    const float* v_in  = (const float*)d_in[2];
    const float* w_in  = (const float*)d_in[3];
    const float* b_in  = (const float*)d_in[4];
    const float* w_out = (const float*)d_in[5];
    const float* b_out = (const float*)d_in[6];

    // ws layout (40 MiB):
    //   [ 0,12M) xbf bf16 [xq|xk|xv]     [12M,18M) Wibf bf16
    //   [18M,20M) Wobf bf16
    //   [20M,24M) qslab bf16 [b][t][e]   [24M,28M) kslab bf16 [b][t][e]
    //   [28M,32M) ktb bf16 [b][e][t]     [32M,36M) vtb bf16 [b][e][t]
    //   [36M,40M) attnbf bf16 [b][t][e]
    char* w = (char*)d_ws;
    unsigned short* xbf    = (unsigned short*)w;
    unsigned short* Wibf   = (unsigned short*)(w + 12582912);
    unsigned short* Wobf   = (unsigned short*)(w + 18874368);
    unsigned short* qslab  = (unsigned short*)(w + 20971520);
    unsigned short* kslab  = (unsigned short*)(w + 25165824);
    unsigned short* ktb    = (unsigned short*)(w + 29360128);
    unsigned short* vtb    = (unsigned short*)(w + 33554432);
    unsigned short* attnbf = (unsigned short*)(w + 37748736);
    float* outp = (float*)d_out;

    k_cast<<<1280, 256, 0, stream>>>(q_in, k_in, v_in, w_in, w_out, xbf);
    k_gin<<<1536, 256, 0, stream>>>(xbf, Wibf, b_in, qslab, kslab, ktb, vtb);
    k_attn<<<512, 256, 0, stream>>>(qslab, kslab, ktb, vtb, attnbf);
    k_gout<<<1024, 256, 0, stream>>>(attnbf, Wobf, b_out, outp);
}